// Round 2
// baseline (442.588 us; speedup 1.0000x reference)
//
#include <hip/hip_runtime.h>
#include <math.h>

#define Bdim 8
#define Sdim 4096
#define Cdim 64
#define Mdim 8
#define Ldim 12
#define H2 512
#define Hdim 256
#define TILE 16

// One block = 16 consecutive sequence positions of one batch. 64 KB LDS:
//   lds[0..8191]      flat tile [16][512]   (phase A out / B in; [0..31] reused for LN stats)
//   lds[8192..16383]  h1 tile   [16][512]   (phase B out); during phase A this region holds
//                       xt  = lds+8192       (27*64 = 1728 floats, staged x window)
//                       mz  = lds+9920       (12*512 = 6144 floats, motifs_z, layout [l][512])
__global__ __launch_bounds__(256) void motifs_fused_kernel(
    const float* __restrict__ x, const float* __restrict__ motifs,
    const float* __restrict__ W1, const float* __restrict__ b1,
    const float* __restrict__ gamma, const float* __restrict__ beta,
    const float* __restrict__ W2, const float* __restrict__ b2,
    float* __restrict__ out)
{
    __shared__ float lds[16384];
    float* flat = lds;            // [16][512]
    float* h1   = lds + 8192;     // [16][512]
    float* xt   = lds + 8192;     // 1728 floats (phase A only)
    float* mz   = lds + 9920;     // 6144 floats (phase A only)
    float* mu_s = lds;            // 16 floats (phase C; flat region dead)
    float* rs_s = lds + 16;       // 16 floats

    const int t   = threadIdx.x;
    const int blk = blockIdx.x;
    const int bi  = blk >> 8;                 // 256 blocks per batch (4096/16)
    const int s0  = (blk & 255) * TILE;
    const float* xb = x + (size_t)bi * Sdim * Cdim;

    // ---- Phase A0: stage x[s0-11 .. s0+15][:] (clamped) + z-norm motifs into LDS ----
    for (int i = t; i < (TILE + Ldim - 1) * Cdim; i += 256) {
        int row = i >> 6, c = i & 63;
        int s = s0 - (Ldim - 1) + row;
        if (s < 0) s = 0;
        xt[i] = xb[(size_t)s * Cdim + c];
    }
    for (int p = t; p < Mdim * Cdim; p += 256) {   // p = m*64 + c
        const float* mp = motifs + p * Ldim;
        float v[Ldim];
        float sm = 0.f;
        #pragma unroll
        for (int l = 0; l < Ldim; ++l) { v[l] = mp[l]; sm += v[l]; }
        float mean = sm * (1.0f / Ldim);
        float sq = 0.f;
        #pragma unroll
        for (int l = 0; l < Ldim; ++l) { float d = v[l] - mean; sq = fmaf(d, d, sq); }
        float sd  = sqrtf(sq * (1.0f / Ldim)) + 1e-8f;
        float inv = 1.0f / sd;
        #pragma unroll
        for (int l = 0; l < Ldim; ++l) mz[l * 512 + p] = (v[l] - mean) * inv;
    }
    __syncthreads();

    // ---- Phase A1: two-pass z-norm windows (direct), dot vs motifs_z, relu^4 -> flat ----
    {
        const int c  = t & 63;
        const int r0 = t >> 6;               // rows r0*4 + q, q=0..3
        float wz[4][Ldim];
        #pragma unroll
        for (int q = 0; q < 4; ++q) {
            const int r = r0 * 4 + q;
            float w[Ldim];
            float sm = 0.f;
            #pragma unroll
            for (int l = 0; l < Ldim; ++l) { w[l] = xt[(r + l) * Cdim + c]; sm += w[l]; }
            float mean = sm * (1.0f / Ldim);
            float sq = 0.f;
            #pragma unroll
            for (int l = 0; l < Ldim; ++l) { float d = w[l] - mean; sq = fmaf(d, d, sq); }
            float sd  = sqrtf(sq * (1.0f / Ldim)) + 1e-8f;
            float inv = 1.0f / sd;
            #pragma unroll
            for (int l = 0; l < Ldim; ++l) wz[q][l] = (w[l] - mean) * inv;
        }
        for (int m = 0; m < Mdim; ++m) {
            float mzv[Ldim];
            #pragma unroll
            for (int l = 0; l < Ldim; ++l) mzv[l] = mz[l * 512 + m * Cdim + c];
            #pragma unroll
            for (int q = 0; q < 4; ++q) {
                float dot = 0.f;
                #pragma unroll
                for (int l = 0; l < Ldim; ++l) dot = fmaf(wz[q][l], mzv[l], dot);
                float sim = dot * (1.0f / Ldim);
                float rv  = fmaxf(sim, 0.f);
                float rv2 = rv * rv;
                flat[(r0 * 4 + q) * H2 + m * Cdim + c] = rv2 * rv2;
            }
        }
    }
    __syncthreads();

    // ---- Phase B: GEMM1 (flat @ W1) + bias + exact gelu -> h1 ----
    {
        float acc0[TILE], acc1[TILE];
        #pragma unroll
        for (int r = 0; r < TILE; ++r) { acc0[r] = 0.f; acc1[r] = 0.f; }
        const int j0 = t, j1 = t + 256;
        for (int k = 0; k < H2; k += 4) {
            const float w00 = W1[(k + 0) * H2 + j0];
            const float w10 = W1[(k + 1) * H2 + j0];
            const float w20 = W1[(k + 2) * H2 + j0];
            const float w30 = W1[(k + 3) * H2 + j0];
            const float w01 = W1[(k + 0) * H2 + j1];
            const float w11 = W1[(k + 1) * H2 + j1];
            const float w21 = W1[(k + 2) * H2 + j1];
            const float w31 = W1[(k + 3) * H2 + j1];
            #pragma unroll
            for (int r = 0; r < TILE; ++r) {
                const float4 f = *reinterpret_cast<const float4*>(&flat[r * H2 + k]);
                acc0[r] = fmaf(f.x, w00, acc0[r]);
                acc0[r] = fmaf(f.y, w10, acc0[r]);
                acc0[r] = fmaf(f.z, w20, acc0[r]);
                acc0[r] = fmaf(f.w, w30, acc0[r]);
                acc1[r] = fmaf(f.x, w01, acc1[r]);
                acc1[r] = fmaf(f.y, w11, acc1[r]);
                acc1[r] = fmaf(f.z, w21, acc1[r]);
                acc1[r] = fmaf(f.w, w31, acc1[r]);
            }
        }
        const float bb0 = b1[j0], bb1 = b1[j1];
        #pragma unroll
        for (int r = 0; r < TILE; ++r) {
            float v0 = acc0[r] + bb0;
            float v1 = acc1[r] + bb1;
            h1[r * H2 + j0] = 0.5f * v0 * (1.f + erff(v0 * 0.70710678118654752f));
            h1[r * H2 + j1] = 0.5f * v1 * (1.f + erff(v1 * 0.70710678118654752f));
        }
    }
    __syncthreads();

    // ---- Phase C: LayerNorm (two-pass) ----
    {
        const int r = t >> 4;            // 0..15
        const int lane = t & 15;
        const float* hr = h1 + r * H2;
        float sm = 0.f;
        for (int i = lane; i < H2; i += 16) sm += hr[i];
        #pragma unroll
        for (int o = 8; o; o >>= 1) sm += __shfl_xor(sm, o);
        const float mu = sm * (1.0f / H2);
        float sq = 0.f;
        for (int i = lane; i < H2; i += 16) { float d = hr[i] - mu; sq = fmaf(d, d, sq); }
        #pragma unroll
        for (int o = 8; o; o >>= 1) sq += __shfl_xor(sq, o);
        if (lane == 0) {
            mu_s[r] = mu;
            rs_s[r] = rsqrtf(sq * (1.0f / H2) + 1e-5f);
        }
    }
    __syncthreads();
    {
        const int j0 = t, j1 = t + 256;
        const float g0 = gamma[j0], g1 = gamma[j1];
        const float be0 = beta[j0], be1 = beta[j1];
        #pragma unroll
        for (int r = 0; r < TILE; ++r) {
            const float mu = mu_s[r], rs = rs_s[r];
            h1[r * H2 + j0] = (h1[r * H2 + j0] - mu) * rs * g0 + be0;
            h1[r * H2 + j1] = (h1[r * H2 + j1] - mu) * rs * g1 + be1;
        }
    }
    __syncthreads();

    // ---- Phase D: GEMM2 (hn @ W2) + bias -> out ----
    {
        float acc[TILE];
        #pragma unroll
        for (int r = 0; r < TILE; ++r) acc[r] = 0.f;
        const int j = t;                 // 0..255
        for (int k = 0; k < H2; k += 4) {
            const float w0 = W2[(k + 0) * Hdim + j];
            const float w1 = W2[(k + 1) * Hdim + j];
            const float w2 = W2[(k + 2) * Hdim + j];
            const float w3 = W2[(k + 3) * Hdim + j];
            #pragma unroll
            for (int r = 0; r < TILE; ++r) {
                const float4 f = *reinterpret_cast<const float4*>(&h1[r * H2 + k]);
                acc[r] = fmaf(f.x, w0, acc[r]);
                acc[r] = fmaf(f.y, w1, acc[r]);
                acc[r] = fmaf(f.z, w2, acc[r]);
                acc[r] = fmaf(f.w, w3, acc[r]);
            }
        }
        const float bb = b2[j];
        float* ob = out + (size_t)(bi * Sdim + s0) * Hdim + j;
        #pragma unroll
        for (int r = 0; r < TILE; ++r) ob[(size_t)r * Hdim] = acc[r] + bb;
    }
}

extern "C" void kernel_launch(void* const* d_in, const int* in_sizes, int n_in,
                              void* d_out, int out_size, void* d_ws, size_t ws_size,
                              hipStream_t stream) {
    const float* x      = (const float*)d_in[0];
    const float* motifs = (const float*)d_in[1];
    const float* W1     = (const float*)d_in[2];
    const float* b1     = (const float*)d_in[3];
    const float* gamma  = (const float*)d_in[4];
    const float* beta   = (const float*)d_in[5];
    const float* W2     = (const float*)d_in[6];
    const float* b2     = (const float*)d_in[7];
    float* out = (float*)d_out;

    const int nblocks = (Bdim * Sdim) / TILE;   // 2048
    motifs_fused_kernel<<<nblocks, 256, 0, stream>>>(
        x, motifs, W1, b1, gamma, beta, W2, b2, out);
}

// Round 3
// 91.252 us; speedup vs baseline: 4.8502x; 4.8502x over previous
//
#include <hip/hip_runtime.h>
#include <math.h>

typedef __attribute__((ext_vector_type(8))) short bf16x8;
typedef __attribute__((ext_vector_type(4))) float f32x4;

#define W1S_OFF 0
#define W2S_OFF 262144
#define MZ_OFF  393216          // motifs_z, [p=m*64+c][16] bf16 (12 used, 4 pad)

__device__ __forceinline__ ushort f2bf(float x){
    union{float f; unsigned u;} v; v.f = x;
    unsigned r = v.u + 0x7fffu + ((v.u >> 16) & 1u);
    return (ushort)(r >> 16);
}
__device__ __forceinline__ float bf2f(ushort u){
    union{unsigned i; float f;} v; v.i = ((unsigned)u) << 16; return v.f;
}

// Pack W1 (512x512) and W2 (512x256) into bf16 MFMA-B-fragment order:
// ws[((tn*16 + tk)*64 + lane)*8 + j] = W[k= tk*32+(lane>>4)*8+j][n= tn*16+(lane&15)]
// Also z-normalize motifs -> bf16 at MZ_OFF.
__global__ __launch_bounds__(256) void prep_kernel(
    const float* __restrict__ W1, const float* __restrict__ W2,
    const float* __restrict__ motifs, ushort* __restrict__ ws)
{
    int idx = blockIdx.x * 256 + threadIdx.x;
    if (idx < 262144) {
        int j = idx & 7, lane = (idx >> 3) & 63, tile = idx >> 9;
        int tk = tile & 15, tn = tile >> 4;
        int k = tk*32 + ((lane>>4)<<3) + j, n = (tn<<4) + (lane&15);
        ws[W1S_OFF + idx] = f2bf(W1[k*512 + n]);
    } else if (idx < 393216) {
        int i = idx - 262144;
        int j = i & 7, lane = (i >> 3) & 63, tile = i >> 9;
        int tk = tile & 15, tn = tile >> 4;
        int k = tk*32 + ((lane>>4)<<3) + j, n = (tn<<4) + (lane&15);
        ws[W2S_OFF + i] = f2bf(W2[k*256 + n]);
    } else if (idx < 393216 + 512) {
        int p = idx - 393216;                  // p = m*64 + c
        const float* mp = motifs + p*12;
        float v[12]; float sm = 0.f;
        #pragma unroll
        for (int l = 0; l < 12; ++l){ v[l] = mp[l]; sm += v[l]; }
        float mean = sm * (1.f/12.f), sq = 0.f;
        #pragma unroll
        for (int l = 0; l < 12; ++l){ float d = v[l]-mean; sq = fmaf(d,d,sq); }
        float inv = 1.f / (sqrtf(sq*(1.f/12.f)) + 1e-8f);
        #pragma unroll
        for (int l = 0; l < 12; ++l) ws[MZ_OFF + p*16 + l] = f2bf((v[l]-mean)*inv);
        #pragma unroll
        for (int l = 12; l < 16; ++l) ws[MZ_OFF + p*16 + l] = 0;
    }
}

// Swizzled byte offset into the [64][512] bf16 LDS tile (conflict-free b128 A-frag reads)
#define SWZ(r, k) (((((r) << 9) + (k)) << 1) ^ (((r) & 7) << 4))

// One block = 64 rows. Phase A (fp32 VALU) -> flat bf16 in LDS -> MFMA GEMM1 ->
// gelu -> LN -> hn bf16 in LDS -> MFMA GEMM2 -> out.
__global__ __launch_bounds__(512, 4) void fused_kernel(
    const float* __restrict__ x, const ushort* __restrict__ ws,
    const float* __restrict__ b1, const float* __restrict__ gamma,
    const float* __restrict__ beta, const float* __restrict__ b2,
    float* __restrict__ out)
{
    __shared__ __align__(16) ushort fl[64*512];   // 64 KB: flat, later hn
    __shared__ float part[64][8][2];              // per-wave LN partials
    __shared__ float mu_s[64];
    __shared__ float rs_s[64];

    const int t  = threadIdx.x;
    const int g0 = blockIdx.x * 64;               // global row base (row = bi*4096+s)

    // ---------------- Phase A: motif correlation -> flat (bf16, swizzled) ----------------
    {
        const int c  = t & 63;
        const int rg = t >> 6;                    // 0..7 -> rows rg*8 .. rg*8+7
        const ushort* mzw = ws + MZ_OFF;
        for (int rq = 0; rq < 2; ++rq) {
            float wz[4][12];
            #pragma unroll
            for (int q = 0; q < 4; ++q) {
                const int r  = rg*8 + rq*4 + q;
                const int gr = g0 + r;
                const int sb = gr & 4095;                 // position within batch
                const size_t base = (size_t)(gr - sb) * 64 + c;
                float w[12]; float sm = 0.f;
                #pragma unroll
                for (int l = 0; l < 12; ++l) {
                    int sw = sb - 11 + l; sw = sw < 0 ? 0 : sw;
                    w[l] = x[base + (size_t)sw * 64]; sm += w[l];
                }
                float mean = sm * (1.f/12.f), sq = 0.f;
                #pragma unroll
                for (int l = 0; l < 12; ++l){ float d = w[l]-mean; sq = fmaf(d,d,sq); }
                float inv = 1.f / (sqrtf(sq*(1.f/12.f)) + 1e-8f);
                #pragma unroll
                for (int l = 0; l < 12; ++l) wz[q][l] = (w[l]-mean)*inv;
            }
            for (int m = 0; m < 8; ++m) {
                const uint* mp32 = (const uint*)(mzw + (m*64 + c)*16);
                float mzv[12];
                #pragma unroll
                for (int h = 0; h < 6; ++h) {
                    uint u = mp32[h];
                    mzv[2*h]   = bf2f((ushort)(u & 0xffffu));
                    mzv[2*h+1] = bf2f((ushort)(u >> 16));
                }
                #pragma unroll
                for (int q = 0; q < 4; ++q) {
                    float dot = 0.f;
                    #pragma unroll
                    for (int l = 0; l < 12; ++l) dot = fmaf(wz[q][l], mzv[l], dot);
                    float sim = dot * (1.f/12.f);
                    float rv  = fmaxf(sim, 0.f);
                    float rv2 = rv * rv;
                    const int r = rg*8 + rq*4 + q, k = m*64 + c;
                    *(ushort*)((char*)fl + SWZ(r, k)) = f2bf(rv2*rv2);
                }
            }
        }
    }
    __syncthreads();

    const int w    = t >> 6;          // wave 0..7
    const int lane = t & 63;
    const int hi   = lane >> 4;
    const int lo   = lane & 15;

    // ---------------- GEMM1: [64 x 512] x [512 x 512], wave n-slice = 64 ----------------
    f32x4 acc[4][4];
    #pragma unroll
    for (int mt = 0; mt < 4; ++mt)
        #pragma unroll
        for (int tn = 0; tn < 4; ++tn)
            acc[mt][tn] = (f32x4){0.f,0.f,0.f,0.f};

    const ushort* ws1 = ws + W1S_OFF;
    const int n0 = w * 64;
    #pragma unroll 2
    for (int tk = 0; tk < 16; ++tk) {
        bf16x8 a[4];
        #pragma unroll
        for (int mt = 0; mt < 4; ++mt)
            a[mt] = *(const bf16x8*)((char*)fl + SWZ(mt*16 + lo, tk*32 + hi*8));
        #pragma unroll
        for (int tn = 0; tn < 4; ++tn) {
            bf16x8 b = *(const bf16x8*)(ws1 + ((((w*4 + tn)*16 + tk)*64 + lane)*8));
            #pragma unroll
            for (int mt = 0; mt < 4; ++mt)
                acc[mt][tn] = __builtin_amdgcn_mfma_f32_16x16x32_bf16(a[mt], b, acc[mt][tn], 0, 0, 0);
        }
    }

    // ---------------- bias + exact gelu (in regs) ----------------
    {
        float b1v[4];
        #pragma unroll
        for (int tn = 0; tn < 4; ++tn) b1v[tn] = b1[n0 + tn*16 + lo];
        #pragma unroll
        for (int mt = 0; mt < 4; ++mt)
            #pragma unroll
            for (int tn = 0; tn < 4; ++tn)
                #pragma unroll
                for (int e = 0; e < 4; ++e) {
                    float v = acc[mt][tn][e] + b1v[tn];
                    acc[mt][tn][e] = 0.5f * v * (1.f + erff(v * 0.70710678118654752f));
                }
    }

    // ---------------- LayerNorm: partials -> stats -> normalize -> hn bf16 LDS ----------------
    #pragma unroll
    for (int mt = 0; mt < 4; ++mt)
        #pragma unroll
        for (int e = 0; e < 4; ++e) {
            float s1 = 0.f, s2 = 0.f;
            #pragma unroll
            for (int tn = 0; tn < 4; ++tn) {
                float g = acc[mt][tn][e];
                s1 += g; s2 = fmaf(g, g, s2);
            }
            #pragma unroll
            for (int o = 1; o < 16; o <<= 1) {
                s1 += __shfl_xor(s1, o);
                s2 += __shfl_xor(s2, o);
            }
            if (lo == 0) {
                int row = mt*16 + hi*4 + e;
                part[row][w][0] = s1;
                part[row][w][1] = s2;
            }
        }
    __syncthreads();
    if (t < 64) {
        float s1 = 0.f, s2 = 0.f;
        #pragma unroll
        for (int ww = 0; ww < 8; ++ww) { s1 += part[t][ww][0]; s2 += part[t][ww][1]; }
        float mu  = s1 * (1.f/512.f);
        float var = s2 * (1.f/512.f) - mu*mu;
        mu_s[t] = mu;
        rs_s[t] = rsqrtf(var + 1e-5f);
    }
    __syncthreads();
    {
        float gv[4], bv[4];
        #pragma unroll
        for (int tn = 0; tn < 4; ++tn) {
            gv[tn] = gamma[n0 + tn*16 + lo];
            bv[tn] = beta[n0 + tn*16 + lo];
        }
        #pragma unroll
        for (int mt = 0; mt < 4; ++mt)
            #pragma unroll
            for (int e = 0; e < 4; ++e) {
                int row = mt*16 + hi*4 + e;
                float mu = mu_s[row], rs = rs_s[row];
                #pragma unroll
                for (int tn = 0; tn < 4; ++tn) {
                    float hn = (acc[mt][tn][e] - mu) * rs * gv[tn] + bv[tn];
                    int col = n0 + tn*16 + lo;
                    *(ushort*)((char*)fl + SWZ(row, col)) = f2bf(hn);
                }
            }
    }
    __syncthreads();

    // ---------------- GEMM2: [64 x 512] x [512 x 256], wave n-slice = 32 ----------------
    f32x4 acc2[4][2];
    #pragma unroll
    for (int mt = 0; mt < 4; ++mt)
        #pragma unroll
        for (int tn = 0; tn < 2; ++tn)
            acc2[mt][tn] = (f32x4){0.f,0.f,0.f,0.f};

    const ushort* ws2 = ws + W2S_OFF;
    #pragma unroll 2
    for (int tk = 0; tk < 16; ++tk) {
        bf16x8 a[4];
        #pragma unroll
        for (int mt = 0; mt < 4; ++mt)
            a[mt] = *(const bf16x8*)((char*)fl + SWZ(mt*16 + lo, tk*32 + hi*8));
        #pragma unroll
        for (int tn = 0; tn < 2; ++tn) {
            bf16x8 b = *(const bf16x8*)(ws2 + ((((w*2 + tn)*16 + tk)*64 + lane)*8));
            #pragma unroll
            for (int mt = 0; mt < 4; ++mt)
                acc2[mt][tn] = __builtin_amdgcn_mfma_f32_16x16x32_bf16(a[mt], b, acc2[mt][tn], 0, 0, 0);
        }
    }

    // ---------------- + b2 -> out ----------------
    {
        const int n2 = w * 32;
        float b2v[2];
        #pragma unroll
        for (int tn = 0; tn < 2; ++tn) b2v[tn] = b2[n2 + tn*16 + lo];
        #pragma unroll
        for (int mt = 0; mt < 4; ++mt)
            #pragma unroll
            for (int tn = 0; tn < 2; ++tn) {
                int col = n2 + tn*16 + lo;
                #pragma unroll
                for (int e = 0; e < 4; ++e) {
                    int row = mt*16 + hi*4 + e;
                    out[(size_t)(g0 + row) * 256 + col] = acc2[mt][tn][e] + b2v[tn];
                }
            }
    }
}

extern "C" void kernel_launch(void* const* d_in, const int* in_sizes, int n_in,
                              void* d_out, int out_size, void* d_ws, size_t ws_size,
                              hipStream_t stream) {
    const float* x      = (const float*)d_in[0];
    const float* motifs = (const float*)d_in[1];
    const float* W1     = (const float*)d_in[2];
    const float* b1     = (const float*)d_in[3];
    const float* gamma  = (const float*)d_in[4];
    const float* beta   = (const float*)d_in[5];
    const float* W2     = (const float*)d_in[6];
    const float* b2     = (const float*)d_in[7];
    float* out = (float*)d_out;
    ushort* ws = (ushort*)d_ws;

    prep_kernel<<<(393216 + 512 + 255) / 256, 256, 0, stream>>>(W1, W2, motifs, ws);
    fused_kernel<<<512, 512, 0, stream>>>(x, ws, b1, gamma, beta, b2, out);
}